// Round 4
// baseline (299.767 us; speedup 1.0000x reference)
//
#include <hip/hip_runtime.h>
#include <math.h>

#define NB 8
#define NA 512
#define NN 64
#define ND 128
#define NF 128
#define NG 25
#define NGA 512

typedef __attribute__((ext_vector_type(8))) short bf16x8;
typedef __attribute__((ext_vector_type(4))) float f32x4;

__device__ __forceinline__ float sspf(float v) {
  // shifted softplus via HW exp/log: max(v,0) + log(1+exp(-|v|)) - ln2
  return fmaxf(v, 0.0f) + __logf(1.0f + __expf(-fabsf(v))) - 0.6931471805599453f;
}

__device__ __forceinline__ short f2bf(float x) {
  union { float f; unsigned u; } v; v.f = x;
  unsigned r = v.u + 0x7fffu + ((v.u >> 16) & 1u);   // RNE
  return (short)(r >> 16);
}

// pack two fp32 -> packed bf16x2 (RNE)
__device__ __forceinline__ unsigned pk2bf(float a, float b) {
  union { float f; unsigned u; } x, y; x.f = a; y.f = b;
  const unsigned ra = (x.u + 0x7fffu + ((x.u >> 16) & 1u)) >> 16;
  const unsigned rb = (y.u + 0x7fffu + ((y.u >> 16) & 1u)) & 0xffff0000u;
  return ra | rb;
}

// ---------------- x = embedding[atomic_numbers] (fp32 + bf16 copy) ----------------
__global__ __launch_bounds__(128) void k_init(const int* __restrict__ zn,
                                              const float* __restrict__ emb,
                                              float* __restrict__ x,
                                              short* __restrict__ xB) {
  const int ba = blockIdx.x;
  const float v = emb[(size_t)zn[ba] * ND + threadIdx.x];
  x[(size_t)ba * ND + threadIdx.x] = v;
  xB[(size_t)ba * ND + threadIdx.x] = f2bf(v);
}

// ---------------- prep: bf16 (transposed) copies of everything GEMM-shaped ----------
#define NGI (NB * NA * NGA)      // 2097152
#define NW1 (3 * 128 * 32)       // 12288
#define NSQ (3 * 128 * 128)      // 49152
#define NAW (3 * 128 * 512)      // 196608
__global__ __launch_bounds__(256) void k_prep(
    const float* __restrict__ Gi, const float* __restrict__ fw1,
    const float* __restrict__ fw2, const float* __restrict__ in2f,
    const float* __restrict__ f2o, const float* __restrict__ dw,
    const float* __restrict__ aw,
    short* __restrict__ GiB, short* __restrict__ w1T, short* __restrict__ w2T,
    short* __restrict__ in2fT, short* __restrict__ f2oT, short* __restrict__ dwT,
    short* __restrict__ awT) {
  int idx = blockIdx.x * 256 + threadIdx.x;
  if (idx < NGI) { GiB[idx] = f2bf(Gi[idx]); return; }
  idx -= NGI;
  if (idx < NW1) {
    const int l = idx >> 12, r = idx & 4095, n = r >> 5, k = r & 31;
    w1T[idx] = (k < NG) ? f2bf(fw1[(size_t)l * NG * NF + k * NF + n]) : (short)0;
    return;
  }
  idx -= NW1;
  if (idx < 4 * NSQ) {
    const int which = idx / NSQ, q = idx % NSQ;
    const int l = q >> 14, r = q & 16383, n = r >> 7, k = r & 127;
    const float* src = (which == 0) ? fw2 : (which == 1) ? in2f : (which == 2) ? f2o : dw;
    short* dst = (which == 0) ? w2T : (which == 1) ? in2fT : (which == 2) ? f2oT : dwT;
    dst[q] = f2bf(src[(size_t)l * 16384 + k * 128 + n]);
    return;
  }
  idx -= 4 * NSQ;
  if (idx < NAW) {
    const int l = idx >> 16, r = idx & 65535, n = r >> 9, k = r & 511;
    awT[idx] = f2bf(aw[(size_t)l * 65536 + k * 128 + n]);
  }
}

// ---------------- y = xB @ in2fT[0]  (MFMA swapped-operand, 16 rows/block) --------
// mfma(A=weightsT-frag, B=data-frag): lane holds row=lanelo, cols=wbase+ct*16+quad*4+reg
__global__ __launch_bounds__(256) void k_lin(const short* __restrict__ xB,
                                             const short* __restrict__ WT,
                                             float* __restrict__ y) {
  const int t = threadIdx.x;
  const int lane = t & 63, wave = t >> 6;
  const int lanelo = lane & 15, quad = lane >> 4;
  const int wbase = wave << 5;
  const int row0 = blockIdx.x << 4;
  f32x4 c[2] = {{0.f, 0.f, 0.f, 0.f}, {0.f, 0.f, 0.f, 0.f}};
#pragma unroll
  for (int kt = 0; kt < 4; ++kt) {
    const bf16x8 b = *(const bf16x8*)(xB + (size_t)(row0 + lanelo) * 128 + kt * 32 + quad * 8);
#pragma unroll
    for (int ct = 0; ct < 2; ++ct) {
      const bf16x8 a = *(const bf16x8*)(WT + (wbase + ct * 16 + lanelo) * 128 + kt * 32 + quad * 8);
      c[ct] = __builtin_amdgcn_mfma_f32_16x16x32_bf16(a, b, c[ct], 0, 0, 0);
    }
  }
#pragma unroll
  for (int ct = 0; ct < 2; ++ct) {
    float4 o = make_float4(c[ct][0], c[ct][1], c[ct][2], c[ct][3]);
    *(float4*)(y + (size_t)(row0 + lanelo) * 128 + wbase + ct * 16 + quad * 4) = o;
  }
}

// ---------------- fused CFConv with MFMA filter network (swapped operands) --------
#define HPAD 136
#define FPAD 40
__global__ __launch_bounds__(128) void k_cfconv(
    const float* __restrict__ pos, const int* __restrict__ nbr,
    const int* __restrict__ nmask, const float* __restrict__ y,
    const short* __restrict__ w1T, const float* __restrict__ b1,
    const short* __restrict__ w2T, const float* __restrict__ b2,
    short* __restrict__ aggB) {
  __shared__ alignas(16) short sFT[NN * FPAD];   // f rows [j][g<=32]; aliased as sPart later
  __shared__ alignas(16) short sH[NN * HPAD];    // h rows [j][f] bf16
  __shared__ float sScale[NN];
  __shared__ int sNbr[NN];

  const int t = threadIdx.x;
  const int ga = blockIdx.x;
  const int b0 = ga & ~(NA - 1);
  const int lane = t & 63;
  const int wave = t >> 6;
  const int lanelo = lane & 15;
  const int quad = lane >> 4;
  const int wbase = wave << 6;

  // A-operand weight fragments (broadcast across blocks -> L2)
  bf16x8 bw1[4];
  bf16x8 bw2[16];
#pragma unroll
  for (int ct = 0; ct < 4; ++ct) {
    const int n = wbase + ct * 16 + lanelo;
    bw1[ct] = *(const bf16x8*)(w1T + n * 32 + quad * 8);
#pragma unroll
    for (int kt = 0; kt < 4; ++kt)
      bw2[ct * 4 + kt] = *(const bf16x8*)(w2T + n * 128 + kt * 32 + quad * 8);
  }
  // bias slices: 4 consecutive f per lane per ct
  float4 b1v[4], b2v[4];
#pragma unroll
  for (int ct = 0; ct < 4; ++ct) {
    const int f0 = wbase + ct * 16 + quad * 4;
    b1v[ct] = *(const float4*)(b1 + f0);
    b2v[ct] = *(const float4*)(b2 + f0);
  }

  if (t < NN) {
    const int nj = nbr[(size_t)ga * NN + t];
    sNbr[t] = nj;
    const float px = pos[(size_t)ga * 3];
    const float py = pos[(size_t)ga * 3 + 1];
    const float pz = pos[(size_t)ga * 3 + 2];
    const float* pj = pos + (size_t)(b0 + nj) * 3;
    const float dx = pj[0] - px, dy = pj[1] - py, dz = pj[2] - pz;
    const float r = sqrtf(dx * dx + dy * dy + dz * dz + 1e-12f);
    sScale[t] = (r <= 5.0f && nmask[(size_t)ga * NN + t] != 0) ? 1.0f : 0.0f;
    const float step = 3.8f / 24.0f;
    const float coef = -0.5f / (step * step);
    short* fr = sFT + t * FPAD;
#pragma unroll
    for (int g = 0; g < NG; ++g) {
      const float d = r - (1.2f + step * (float)g);
      fr[g] = f2bf(__expf(coef * d * d));
    }
#pragma unroll
    for (int g = NG; g < 32; ++g) fr[g] = 0;
  }
  __syncthreads();

  // phase 1: h = ssp(f @ w1 + b1) -> bf16 LDS; lane: j=rt*16+lanelo, f=f0+reg
#pragma unroll
  for (int rt = 0; rt < 4; ++rt) {
    const int j = rt * 16 + lanelo;
    const bf16x8 b = *(const bf16x8*)(sFT + j * FPAD + quad * 8);
#pragma unroll
    for (int ct = 0; ct < 4; ++ct) {
      f32x4 c = {0.f, 0.f, 0.f, 0.f};
      c = __builtin_amdgcn_mfma_f32_16x16x32_bf16(bw1[ct], b, c, 0, 0, 0);
      const int f0 = wbase + ct * 16 + quad * 4;
      const float h0 = sspf(c[0] + b1v[ct].x);
      const float h1 = sspf(c[1] + b1v[ct].y);
      const float h2 = sspf(c[2] + b1v[ct].z);
      const float h3 = sspf(c[3] + b1v[ct].w);
      uint2 pk; pk.x = pk2bf(h0, h1); pk.y = pk2bf(h2, h3);
      *(uint2*)(sH + j * HPAD + f0) = pk;
    }
  }
  __syncthreads();

  // phase 2: W = h @ w2; consume against vectorized y gathers
  f32x4 pagg[4] = {{0.f,0.f,0.f,0.f},{0.f,0.f,0.f,0.f},{0.f,0.f,0.f,0.f},{0.f,0.f,0.f,0.f}};
#pragma unroll
  for (int rt = 0; rt < 4; ++rt) {
    const int j = rt * 16 + lanelo;
    const float sc = sScale[j];
    const int nj = sNbr[j];
    const float* yrow = y + (size_t)(b0 + nj) * NF;
    f32x4 acc[4];
#pragma unroll
    for (int ct = 0; ct < 4; ++ct) acc[ct] = (f32x4){0.f, 0.f, 0.f, 0.f};
#pragma unroll
    for (int kt = 0; kt < 4; ++kt) {
      const bf16x8 b = *(const bf16x8*)(sH + j * HPAD + kt * 32 + quad * 8);
#pragma unroll
      for (int ct = 0; ct < 4; ++ct)
        acc[ct] = __builtin_amdgcn_mfma_f32_16x16x32_bf16(bw2[ct * 4 + kt], b, acc[ct], 0, 0, 0);
    }
#pragma unroll
    for (int ct = 0; ct < 4; ++ct) {
      const int f0 = wbase + ct * 16 + quad * 4;
      const float4 yv = *(const float4*)(yrow + f0);
      pagg[ct][0] = fmaf(sc * (acc[ct][0] + b2v[ct].x), yv.x, pagg[ct][0]);
      pagg[ct][1] = fmaf(sc * (acc[ct][1] + b2v[ct].y), yv.y, pagg[ct][1]);
      pagg[ct][2] = fmaf(sc * (acc[ct][2] + b2v[ct].z), yv.z, pagg[ct][2]);
      pagg[ct][3] = fmaf(sc * (acc[ct][3] + b2v[ct].w), yv.w, pagg[ct][3]);
    }
  }

  // butterfly reduce over the 16 lanelo lanes (j dim)
#pragma unroll
  for (int mask = 1; mask <= 8; mask <<= 1) {
#pragma unroll
    for (int ct = 0; ct < 4; ++ct) {
#pragma unroll
      for (int reg = 0; reg < 4; ++reg)
        pagg[ct][reg] += __shfl_xor(pagg[ct][reg], mask, 64);
    }
  }
  float* sPart = (float*)sFT;   // sFT idle after phase 1
  if (lanelo == 0) {
#pragma unroll
    for (int ct = 0; ct < 4; ++ct) {
      const int f0 = wbase + ct * 16 + quad * 4;
      *(float4*)(sPart + f0) = make_float4(pagg[ct][0], pagg[ct][1], pagg[ct][2], pagg[ct][3]);
    }
  }
  __syncthreads();
  aggB[(size_t)ga * NF + t] = f2bf(sPart[t]);
}

// ---------------- per-layer update (all-MFMA, swapped operands) ----------------
// t1 = aggB@f2oT + b; v = t1@dwT + db + GiB@awT; x += ssp(v); y = x_new@in2fT
#define TPAD 136
__global__ __launch_bounds__(256) void k_upd(
    float* __restrict__ x, const short* __restrict__ aggB,
    const short* __restrict__ GiB,
    const short* __restrict__ f2oT, const float* __restrict__ f2ob,
    const short* __restrict__ dwT, const float* __restrict__ db,
    const short* __restrict__ awT, const short* __restrict__ in2fT,
    float* __restrict__ yout) {
  __shared__ alignas(16) short sT[16 * TPAD];
  const int t = threadIdx.x;
  const int lane = t & 63, wave = t >> 6;
  const int lanelo = lane & 15, quad = lane >> 4;
  const int wbase = wave << 5;               // 4 waves x 32 cols
  const int row0 = blockIdx.x << 4;
  const int row = row0 + lanelo;

  // GEMM1: t1 = aggB @ f2oT + f2ob  -> bf16 LDS (lane: row=lanelo, 4 consecutive cols)
  f32x4 c1[2] = {{0.f, 0.f, 0.f, 0.f}, {0.f, 0.f, 0.f, 0.f}};
#pragma unroll
  for (int kt = 0; kt < 4; ++kt) {
    const bf16x8 b = *(const bf16x8*)(aggB + (size_t)row * 128 + kt * 32 + quad * 8);
#pragma unroll
    for (int ct = 0; ct < 2; ++ct) {
      const bf16x8 a = *(const bf16x8*)(f2oT + (wbase + ct * 16 + lanelo) * 128 + kt * 32 + quad * 8);
      c1[ct] = __builtin_amdgcn_mfma_f32_16x16x32_bf16(a, b, c1[ct], 0, 0, 0);
    }
  }
#pragma unroll
  for (int ct = 0; ct < 2; ++ct) {
    const int c0 = wbase + ct * 16 + quad * 4;
    const float4 bv = *(const float4*)(f2ob + c0);
    uint2 pk;
    pk.x = pk2bf(c1[ct][0] + bv.x, c1[ct][1] + bv.y);
    pk.y = pk2bf(c1[ct][2] + bv.z, c1[ct][3] + bv.w);
    *(uint2*)(sT + lanelo * TPAD + c0) = pk;
  }
  __syncthreads();

  // GEMM2 (t1@dwT, K=128) + GEMM3 (GiB@awT, K=512)
  f32x4 c2[2] = {{0.f, 0.f, 0.f, 0.f}, {0.f, 0.f, 0.f, 0.f}};
#pragma unroll
  for (int kt = 0; kt < 4; ++kt) {
    const bf16x8 b = *(const bf16x8*)(sT + lanelo * TPAD + kt * 32 + quad * 8);
#pragma unroll
    for (int ct = 0; ct < 2; ++ct) {
      const bf16x8 a = *(const bf16x8*)(dwT + (wbase + ct * 16 + lanelo) * 128 + kt * 32 + quad * 8);
      c2[ct] = __builtin_amdgcn_mfma_f32_16x16x32_bf16(a, b, c2[ct], 0, 0, 0);
    }
  }
#pragma unroll
  for (int kt = 0; kt < 16; ++kt) {
    const bf16x8 b = *(const bf16x8*)(GiB + (size_t)row * NGA + kt * 32 + quad * 8);
#pragma unroll
    for (int ct = 0; ct < 2; ++ct) {
      const bf16x8 a = *(const bf16x8*)(awT + (wbase + ct * 16 + lanelo) * NGA + kt * 32 + quad * 8);
      c2[ct] = __builtin_amdgcn_mfma_f32_16x16x32_bf16(a, b, c2[ct], 0, 0, 0);
    }
  }
  __syncthreads();   // sT reads done

  // epilogue: x += ssp(v); stage x_new bf16 for GEMM4
#pragma unroll
  for (int ct = 0; ct < 2; ++ct) {
    const int c0 = wbase + ct * 16 + quad * 4;
    const float4 dv = *(const float4*)(db + c0);
    float* xp = x + (size_t)row * 128 + c0;
    const float4 xv = *(const float4*)xp;
    float4 xo;
    xo.x = xv.x + sspf(c2[ct][0] + dv.x);
    xo.y = xv.y + sspf(c2[ct][1] + dv.y);
    xo.z = xv.z + sspf(c2[ct][2] + dv.z);
    xo.w = xv.w + sspf(c2[ct][3] + dv.w);
    *(float4*)xp = xo;
    if (in2fT != nullptr) {
      uint2 pk; pk.x = pk2bf(xo.x, xo.y); pk.y = pk2bf(xo.z, xo.w);
      *(uint2*)(sT + lanelo * TPAD + c0) = pk;
    }
  }
  if (in2fT == nullptr) return;
  __syncthreads();

  // GEMM4: y = x_new @ in2fT
  f32x4 c3[2] = {{0.f, 0.f, 0.f, 0.f}, {0.f, 0.f, 0.f, 0.f}};
#pragma unroll
  for (int kt = 0; kt < 4; ++kt) {
    const bf16x8 b = *(const bf16x8*)(sT + lanelo * TPAD + kt * 32 + quad * 8);
#pragma unroll
    for (int ct = 0; ct < 2; ++ct) {
      const bf16x8 a = *(const bf16x8*)(in2fT + (wbase + ct * 16 + lanelo) * 128 + kt * 32 + quad * 8);
      c3[ct] = __builtin_amdgcn_mfma_f32_16x16x32_bf16(a, b, c3[ct], 0, 0, 0);
    }
  }
#pragma unroll
  for (int ct = 0; ct < 2; ++ct) {
    float4 o = make_float4(c3[ct][0], c3[ct][1], c3[ct][2], c3[ct][3]);
    *(float4*)(yout + (size_t)row * 128 + wbase + ct * 16 + quad * 4) = o;
  }
}

extern "C" void kernel_launch(void* const* d_in, const int* in_sizes, int n_in,
                              void* d_out, int out_size, void* d_ws, size_t ws_size,
                              hipStream_t stream) {
  (void)in_sizes; (void)n_in; (void)out_size; (void)ws_size;
  const int* zn = (const int*)d_in[0];
  const float* pos = (const float*)d_in[1];
  const int* nbr = (const int*)d_in[2];
  const int* nmask = (const int*)d_in[3];
  const float* Gi = (const float*)d_in[4];
  const float* emb = (const float*)d_in[5];
  const float* fw1 = (const float*)d_in[6];
  const float* fb1 = (const float*)d_in[7];
  const float* fw2 = (const float*)d_in[8];
  const float* fb2 = (const float*)d_in[9];
  const float* in2f = (const float*)d_in[10];
  const float* f2o = (const float*)d_in[11];
  const float* f2ob = (const float*)d_in[12];
  const float* dwp = (const float*)d_in[13];
  const float* dbp = (const float*)d_in[14];
  const float* awp = (const float*)d_in[15];

  float* x = (float*)d_out;                          // [B,A,D] fp32
  float* y = (float*)d_ws;                           // [B,A,F] fp32
  short* aggB = (short*)(y + (size_t)NB * NA * NF);  // [B,A,F] bf16
  short* xB = aggB + (size_t)NB * NA * NF;           // [B,A,D] bf16
  short* GiB = xB + (size_t)NB * NA * ND;            // [B,A,GA] bf16
  short* w1T = GiB + (size_t)NGI;                    // [3][128][32]
  short* w2T = w1T + NW1;                            // [3][128][128]
  short* in2fT = w2T + NSQ;
  short* f2oT = in2fT + NSQ;
  short* dwT = f2oT + NSQ;
  short* awT = dwT + NSQ;                            // [3][128][512]

  const int prep_total = NGI + NW1 + 4 * NSQ + NAW;
  k_prep<<<(prep_total + 255) / 256, 256, 0, stream>>>(
      Gi, fw1, fw2, in2f, f2o, dwp, awp, GiB, w1T, w2T, in2fT, f2oT, dwT, awT);
  k_init<<<NB * NA, 128, 0, stream>>>(zn, emb, x, xB);
  k_lin<<<NB * NA / 16, 256, 0, stream>>>(xB, in2fT, y);
  for (int l = 0; l < 3; ++l) {
    k_cfconv<<<NB * NA, 128, 0, stream>>>(pos, nbr, nmask, y,
        w1T + (size_t)l * 128 * 32, fb1 + (size_t)l * NF,
        w2T + (size_t)l * 128 * 128, fb2 + (size_t)l * NF, aggB);
    k_upd<<<NB * NA / 16, 256, 0, stream>>>(x, aggB, GiB,
        f2oT + (size_t)l * NSQ / 3, f2ob + (size_t)l * ND,
        dwT + (size_t)l * NSQ / 3, dbp + (size_t)l * ND,
        awT + (size_t)l * NAW / 3,
        (l < 2) ? (in2fT + (size_t)(l + 1) * NSQ / 3) : nullptr, y);
  }
}

// Round 5
// 272.988 us; speedup vs baseline: 1.0981x; 1.0981x over previous
//
#include <hip/hip_runtime.h>
#include <math.h>

#define NB 8
#define NA 512
#define NN 64
#define ND 128
#define NF 128
#define NG 25
#define NGA 512

typedef __attribute__((ext_vector_type(8))) short bf16x8;
typedef __attribute__((ext_vector_type(4))) float f32x4;

__device__ __forceinline__ float sspf(float v) {
  // shifted softplus via HW exp/log: max(v,0) + log(1+exp(-|v|)) - ln2
  return fmaxf(v, 0.0f) + __logf(1.0f + __expf(-fabsf(v))) - 0.6931471805599453f;
}

__device__ __forceinline__ short f2bf(float x) {
  union { float f; unsigned u; } v; v.f = x;
  unsigned r = v.u + 0x7fffu + ((v.u >> 16) & 1u);   // RNE
  return (short)(r >> 16);
}

__device__ __forceinline__ unsigned pk2bf(float a, float b) {
  union { float f; unsigned u; } x, y; x.f = a; y.f = b;
  const unsigned ra = (x.u + 0x7fffu + ((x.u >> 16) & 1u)) >> 16;
  const unsigned rb = (y.u + 0x7fffu + ((y.u >> 16) & 1u)) & 0xffff0000u;
  return ra | rb;
}

// ---------------- prep: bf16 (transposed) copies of everything GEMM-shaped ----------
#define NGI (NB * NA * NGA)      // 2097152
#define NW1 (3 * 128 * 32)       // 12288
#define NSQ (3 * 128 * 128)      // 49152
#define NAW (3 * 128 * 512)      // 196608
__global__ __launch_bounds__(256) void k_prep(
    const float* __restrict__ Gi, const float* __restrict__ fw1,
    const float* __restrict__ fw2, const float* __restrict__ in2f,
    const float* __restrict__ f2o, const float* __restrict__ dw,
    const float* __restrict__ aw,
    short* __restrict__ GiB, short* __restrict__ w1T, short* __restrict__ w2T,
    short* __restrict__ in2fT, short* __restrict__ f2oT, short* __restrict__ dwT,
    short* __restrict__ awT) {
  int idx = blockIdx.x * 256 + threadIdx.x;
  if (idx < NGI) { GiB[idx] = f2bf(Gi[idx]); return; }
  idx -= NGI;
  if (idx < NW1) {
    const int l = idx >> 12, r = idx & 4095, n = r >> 5, k = r & 31;
    w1T[idx] = (k < NG) ? f2bf(fw1[(size_t)l * NG * NF + k * NF + n]) : (short)0;
    return;
  }
  idx -= NW1;
  if (idx < 4 * NSQ) {
    const int which = idx / NSQ, q = idx % NSQ;
    const int l = q >> 14, r = q & 16383, n = r >> 7, k = r & 127;
    const float* src = (which == 0) ? fw2 : (which == 1) ? in2f : (which == 2) ? f2o : dw;
    short* dst = (which == 0) ? w2T : (which == 1) ? in2fT : (which == 2) ? f2oT : dwT;
    dst[q] = f2bf(src[(size_t)l * 16384 + k * 128 + n]);
    return;
  }
  idx -= 4 * NSQ;
  if (idx < NAW) {
    const int l = idx >> 16, r = idx & 65535, n = r >> 9, k = r & 511;
    awT[idx] = f2bf(aw[(size_t)l * 65536 + k * 128 + n]);
  }
}

// ---------------- fused init + first projection: x = emb[zn]; y = x @ in2fT[0] -----
// swapped-operand MFMA: lane holds row=lanelo, cols = wbase+ct*16+quad*4+reg
__global__ __launch_bounds__(256) void k_initlin(const int* __restrict__ zn,
                                                 const float* __restrict__ emb,
                                                 const short* __restrict__ WT,
                                                 float* __restrict__ x,
                                                 float* __restrict__ y) {
  const int t = threadIdx.x;
  const int lane = t & 63, wave = t >> 6;
  const int lanelo = lane & 15, quad = lane >> 4;
  const int wbase = wave << 5;
  const int row0 = blockIdx.x << 4;
  const int row = row0 + lanelo;
  const float* erow = emb + (size_t)zn[row] * ND;
  f32x4 c[2] = {{0.f, 0.f, 0.f, 0.f}, {0.f, 0.f, 0.f, 0.f}};
#pragma unroll
  for (int kt = 0; kt < 4; ++kt) {
    const int k0 = kt * 32 + quad * 8;
    const float4 e0 = *(const float4*)(erow + k0);
    const float4 e1 = *(const float4*)(erow + k0 + 4);
    if (wave == 0) {   // wave 0 alone covers all 16x128 elements across kt/quad
      *(float4*)(x + (size_t)row * ND + k0) = e0;
      *(float4*)(x + (size_t)row * ND + k0 + 4) = e1;
    }
    bf16x8 b;
    b[0] = f2bf(e0.x); b[1] = f2bf(e0.y); b[2] = f2bf(e0.z); b[3] = f2bf(e0.w);
    b[4] = f2bf(e1.x); b[5] = f2bf(e1.y); b[6] = f2bf(e1.z); b[7] = f2bf(e1.w);
#pragma unroll
    for (int ct = 0; ct < 2; ++ct) {
      const bf16x8 a = *(const bf16x8*)(WT + (wbase + ct * 16 + lanelo) * 128 + k0);
      c[ct] = __builtin_amdgcn_mfma_f32_16x16x32_bf16(a, b, c[ct], 0, 0, 0);
    }
  }
#pragma unroll
  for (int ct = 0; ct < 2; ++ct) {
    float4 o = make_float4(c[ct][0], c[ct][1], c[ct][2], c[ct][3]);
    *(float4*)(y + (size_t)row * 128 + wbase + ct * 16 + quad * 4) = o;
  }
}

// ---------------- hoisted angular GEMM: vang[l] = GiB @ awT[l] ----------------
__global__ __launch_bounds__(256) void k_vang(const short* __restrict__ GiB,
                                              const short* __restrict__ awT,
                                              float* __restrict__ vang) {
  const int t = threadIdx.x;
  const int lane = t & 63, wave = t >> 6;
  const int lanelo = lane & 15, quad = lane >> 4;
  const int wbase = wave << 5;
  const int l = blockIdx.y;
  const int row = (blockIdx.x << 4) + lanelo;
  const short* aw = awT + (size_t)l * 128 * NGA;
  f32x4 c[2] = {{0.f, 0.f, 0.f, 0.f}, {0.f, 0.f, 0.f, 0.f}};
#pragma unroll
  for (int kt = 0; kt < 16; ++kt) {
    const int k0 = kt * 32 + quad * 8;
    const bf16x8 b = *(const bf16x8*)(GiB + (size_t)row * NGA + k0);
#pragma unroll
    for (int ct = 0; ct < 2; ++ct) {
      const bf16x8 a = *(const bf16x8*)(aw + (size_t)(wbase + ct * 16 + lanelo) * NGA + k0);
      c[ct] = __builtin_amdgcn_mfma_f32_16x16x32_bf16(a, b, c[ct], 0, 0, 0);
    }
  }
  float* vrow = vang + ((size_t)l * NB * NA + row) * 128;
#pragma unroll
  for (int ct = 0; ct < 2; ++ct) {
    float4 o = make_float4(c[ct][0], c[ct][1], c[ct][2], c[ct][3]);
    *(float4*)(vrow + wbase + ct * 16 + quad * 4) = o;
  }
}

// ---------------- fused CFConv (round-3 orientation, LDS diet) ----------------
// one atom/block, 128 thr = 2 waves; wave owns f-cols [wave*64, +64)
// phase1 A-frags (gaussians) built on the fly from sR; h bf16 in sH; sPart aliases sH.
#define HPAD 136
__global__ __launch_bounds__(128) void k_cfconv(
    const float* __restrict__ pos, const int* __restrict__ nbr,
    const int* __restrict__ nmask, const float* __restrict__ y,
    const short* __restrict__ w1T, const float* __restrict__ b1,
    const short* __restrict__ w2T, const float* __restrict__ b2,
    short* __restrict__ aggB) {
  __shared__ alignas(16) short sH[NN * HPAD];   // 17408 B; start reused as sPart at end
  __shared__ float sR[NN];
  __shared__ float sScale[NN];
  __shared__ int sNbr[NN];

  const int t = threadIdx.x;
  const int ga = blockIdx.x;
  const int b0 = ga & ~(NA - 1);
  const int lane = t & 63;
  const int wave = t >> 6;
  const int lanelo = lane & 15;
  const int quad = lane >> 4;
  const int wbase = wave << 6;

  // weight B-frags (B[n][k], n = lane&15) — broadcast across blocks -> L2
  bf16x8 bw1[4];
  bf16x8 bw2[16];
#pragma unroll
  for (int ct = 0; ct < 4; ++ct) {
    const int n = wbase + ct * 16 + lanelo;
    bw1[ct] = *(const bf16x8*)(w1T + n * 32 + quad * 8);
#pragma unroll
    for (int kt = 0; kt < 4; ++kt)
      bw2[ct * 4 + kt] = *(const bf16x8*)(w2T + n * 128 + kt * 32 + quad * 8);
  }
  // per-lane bias registers: this lane's f per ct is wbase+ct*16+lanelo
  float b1r[4], b2r[4];
#pragma unroll
  for (int ct = 0; ct < 4; ++ct) {
    b1r[ct] = b1[wbase + ct * 16 + lanelo];
    b2r[ct] = b2[wbase + ct * 16 + lanelo];
  }

  if (t < NN) {
    const int nj = nbr[(size_t)ga * NN + t];
    sNbr[t] = nj;
    const float px = pos[(size_t)ga * 3];
    const float py = pos[(size_t)ga * 3 + 1];
    const float pz = pos[(size_t)ga * 3 + 2];
    const float* pj = pos + (size_t)(b0 + nj) * 3;
    const float dx = pj[0] - px, dy = pj[1] - py, dz = pj[2] - pz;
    const float r = sqrtf(dx * dx + dy * dy + dz * dz + 1e-12f);
    sR[t] = r;
    sScale[t] = (r <= 5.0f && nmask[(size_t)ga * NN + t] != 0) ? 1.0f : 0.0f;
  }
  __syncthreads();

  const float step = 3.8f / 24.0f;
  const float coef = -0.5f / (step * step);

  // ---- phase 1: h = ssp(f @ w1 + b1) -> bf16 LDS ----
#pragma unroll
  for (int rt = 0; rt < 4; ++rt) {
    const float r = sR[rt * 16 + lanelo];
    bf16x8 a;
#pragma unroll
    for (int i = 0; i < 8; ++i) {
      const int g = quad * 8 + i;
      const float d = r - (1.2f + step * (float)g);
      const float e = __expf(coef * d * d);
      a[i] = (g < NG) ? f2bf(e) : (short)0;
    }
#pragma unroll
    for (int ct = 0; ct < 4; ++ct) {
      f32x4 c = {0.f, 0.f, 0.f, 0.f};
      c = __builtin_amdgcn_mfma_f32_16x16x32_bf16(a, bw1[ct], c, 0, 0, 0);
      const int f = wbase + ct * 16 + lanelo;
      const float b1f = b1r[ct];
#pragma unroll
      for (int reg = 0; reg < 4; ++reg) {
        const int j = rt * 16 + quad * 4 + reg;
        sH[j * HPAD + f] = f2bf(sspf(c[reg] + b1f));
      }
    }
  }
  __syncthreads();

  // ---- phase 2: W = h @ w2; consume against y gathers ----
  float pagg[4] = {0.f, 0.f, 0.f, 0.f};
#pragma unroll
  for (int rt = 0; rt < 4; ++rt) {
    f32x4 acc[4];
#pragma unroll
    for (int ct = 0; ct < 4; ++ct) acc[ct] = (f32x4){0.f, 0.f, 0.f, 0.f};
#pragma unroll
    for (int kt = 0; kt < 4; ++kt) {
      const bf16x8 a = *(const bf16x8*)(sH + (rt * 16 + lanelo) * HPAD + kt * 32 + quad * 8);
#pragma unroll
      for (int ct = 0; ct < 4; ++ct)
        acc[ct] = __builtin_amdgcn_mfma_f32_16x16x32_bf16(a, bw2[ct * 4 + kt], acc[ct], 0, 0, 0);
    }
#pragma unroll
    for (int reg = 0; reg < 4; ++reg) {
      const int j = rt * 16 + quad * 4 + reg;
      const float sc = sScale[j];
      const float* yrow = y + (size_t)(b0 + sNbr[j]) * NF + wbase + lanelo;
#pragma unroll
      for (int ct = 0; ct < 4; ++ct)
        pagg[ct] = fmaf(sc * (acc[ct][reg] + b2r[ct]), yrow[ct * 16], pagg[ct]);
    }
  }

  __syncthreads();                 // both waves done reading sH -> alias as sPart
  float* sPart = (float*)sH;
#pragma unroll
  for (int ct = 0; ct < 4; ++ct)
    sPart[quad * NF + wbase + ct * 16 + lanelo] = pagg[ct];
  __syncthreads();
  aggB[(size_t)ga * NF + t] =
      f2bf(sPart[t] + sPart[NF + t] + sPart[2 * NF + t] + sPart[3 * NF + t]);
}

// ---------------- per-layer update (angular hoisted out) ----------------
// t1 = aggB@f2oT + b; v = t1@dwT + db + vang[l]; x += ssp(v); y = x_new@in2fT
#define TPAD 136
__global__ __launch_bounds__(256) void k_upd(
    float* __restrict__ x, const short* __restrict__ aggB,
    const float* __restrict__ vang,
    const short* __restrict__ f2oT, const float* __restrict__ f2ob,
    const short* __restrict__ dwT, const float* __restrict__ db,
    const short* __restrict__ in2fT, float* __restrict__ yout) {
  __shared__ alignas(16) short sT[16 * TPAD];
  const int t = threadIdx.x;
  const int lane = t & 63, wave = t >> 6;
  const int lanelo = lane & 15, quad = lane >> 4;
  const int wbase = wave << 5;               // 4 waves x 32 cols
  const int row0 = blockIdx.x << 4;
  const int row = row0 + lanelo;

  // GEMM1: t1 = aggB @ f2oT + f2ob  -> bf16 LDS
  f32x4 c1[2] = {{0.f, 0.f, 0.f, 0.f}, {0.f, 0.f, 0.f, 0.f}};
#pragma unroll
  for (int kt = 0; kt < 4; ++kt) {
    const bf16x8 b = *(const bf16x8*)(aggB + (size_t)row * 128 + kt * 32 + quad * 8);
#pragma unroll
    for (int ct = 0; ct < 2; ++ct) {
      const bf16x8 a = *(const bf16x8*)(f2oT + (wbase + ct * 16 + lanelo) * 128 + kt * 32 + quad * 8);
      c1[ct] = __builtin_amdgcn_mfma_f32_16x16x32_bf16(a, b, c1[ct], 0, 0, 0);
    }
  }
#pragma unroll
  for (int ct = 0; ct < 2; ++ct) {
    const int c0 = wbase + ct * 16 + quad * 4;
    const float4 bv = *(const float4*)(f2ob + c0);
    uint2 pk;
    pk.x = pk2bf(c1[ct][0] + bv.x, c1[ct][1] + bv.y);
    pk.y = pk2bf(c1[ct][2] + bv.z, c1[ct][3] + bv.w);
    *(uint2*)(sT + lanelo * TPAD + c0) = pk;
  }
  __syncthreads();

  // GEMM2: v = t1 @ dwT  (+ vang added in epilogue)
  f32x4 c2[2] = {{0.f, 0.f, 0.f, 0.f}, {0.f, 0.f, 0.f, 0.f}};
#pragma unroll
  for (int kt = 0; kt < 4; ++kt) {
    const bf16x8 b = *(const bf16x8*)(sT + lanelo * TPAD + kt * 32 + quad * 8);
#pragma unroll
    for (int ct = 0; ct < 2; ++ct) {
      const bf16x8 a = *(const bf16x8*)(dwT + (wbase + ct * 16 + lanelo) * 128 + kt * 32 + quad * 8);
      c2[ct] = __builtin_amdgcn_mfma_f32_16x16x32_bf16(a, b, c2[ct], 0, 0, 0);
    }
  }
  __syncthreads();   // sT reads done

  // epilogue: x += ssp(v + vang + db); stage x_new bf16 for GEMM4
#pragma unroll
  for (int ct = 0; ct < 2; ++ct) {
    const int c0 = wbase + ct * 16 + quad * 4;
    const float4 dv = *(const float4*)(db + c0);
    const float4 vv = *(const float4*)(vang + (size_t)row * 128 + c0);
    float* xp = x + (size_t)row * 128 + c0;
    const float4 xv = *(const float4*)xp;
    float4 xo;
    xo.x = xv.x + sspf(c2[ct][0] + vv.x + dv.x);
    xo.y = xv.y + sspf(c2[ct][1] + vv.y + dv.y);
    xo.z = xv.z + sspf(c2[ct][2] + vv.z + dv.z);
    xo.w = xv.w + sspf(c2[ct][3] + vv.w + dv.w);
    *(float4*)xp = xo;
    if (in2fT != nullptr) {
      uint2 pk; pk.x = pk2bf(xo.x, xo.y); pk.y = pk2bf(xo.z, xo.w);
      *(uint2*)(sT + lanelo * TPAD + c0) = pk;
    }
  }
  if (in2fT == nullptr) return;
  __syncthreads();

  // GEMM4: y = x_new @ in2fT
  f32x4 c3[2] = {{0.f, 0.f, 0.f, 0.f}, {0.f, 0.f, 0.f, 0.f}};
#pragma unroll
  for (int kt = 0; kt < 4; ++kt) {
    const bf16x8 b = *(const bf16x8*)(sT + lanelo * TPAD + kt * 32 + quad * 8);
#pragma unroll
    for (int ct = 0; ct < 2; ++ct) {
      const bf16x8 a = *(const bf16x8*)(in2fT + (wbase + ct * 16 + lanelo) * 128 + kt * 32 + quad * 8);
      c3[ct] = __builtin_amdgcn_mfma_f32_16x16x32_bf16(a, b, c3[ct], 0, 0, 0);
    }
  }
#pragma unroll
  for (int ct = 0; ct < 2; ++ct) {
    float4 o = make_float4(c3[ct][0], c3[ct][1], c3[ct][2], c3[ct][3]);
    *(float4*)(yout + (size_t)row * 128 + wbase + ct * 16 + quad * 4) = o;
  }
}

extern "C" void kernel_launch(void* const* d_in, const int* in_sizes, int n_in,
                              void* d_out, int out_size, void* d_ws, size_t ws_size,
                              hipStream_t stream) {
  (void)in_sizes; (void)n_in; (void)out_size; (void)ws_size;
  const int* zn = (const int*)d_in[0];
  const float* pos = (const float*)d_in[1];
  const int* nbr = (const int*)d_in[2];
  const int* nmask = (const int*)d_in[3];
  const float* Gi = (const float*)d_in[4];
  const float* emb = (const float*)d_in[5];
  const float* fw1 = (const float*)d_in[6];
  const float* fb1 = (const float*)d_in[7];
  const float* fw2 = (const float*)d_in[8];
  const float* fb2 = (const float*)d_in[9];
  const float* in2f = (const float*)d_in[10];
  const float* f2o = (const float*)d_in[11];
  const float* f2ob = (const float*)d_in[12];
  const float* dwp = (const float*)d_in[13];
  const float* dbp = (const float*)d_in[14];
  const float* awp = (const float*)d_in[15];

  float* x = (float*)d_out;                           // [B,A,D] fp32
  float* y = (float*)d_ws;                            // [B,A,F] fp32
  float* vang = y + (size_t)NB * NA * NF;             // [3][B*A][128] fp32
  short* aggB = (short*)(vang + (size_t)3 * NB * NA * ND);  // [B,A,F] bf16
  short* GiB = aggB + (size_t)NB * NA * NF;           // [B,A,GA] bf16
  short* w1T = GiB + (size_t)NGI;                     // [3][128][32]
  short* w2T = w1T + NW1;                             // [3][128][128]
  short* in2fT = w2T + NSQ;
  short* f2oT = in2fT + NSQ;
  short* dwT = f2oT + NSQ;
  short* awT = dwT + NSQ;                             // [3][128][512]

  const int prep_total = NGI + NW1 + 4 * NSQ + NAW;
  k_prep<<<(prep_total + 255) / 256, 256, 0, stream>>>(
      Gi, fw1, fw2, in2f, f2o, dwp, awp, GiB, w1T, w2T, in2fT, f2oT, dwT, awT);
  k_initlin<<<NB * NA / 16, 256, 0, stream>>>(zn, emb, in2fT, x, y);
  k_vang<<<dim3(NB * NA / 16, 3), 256, 0, stream>>>(GiB, awT, vang);
  for (int l = 0; l < 3; ++l) {
    k_cfconv<<<NB * NA, 128, 0, stream>>>(pos, nbr, nmask, y,
        w1T + (size_t)l * 128 * 32, fb1 + (size_t)l * NF,
        w2T + (size_t)l * 128 * 128, fb2 + (size_t)l * NF, aggB);
    k_upd<<<NB * NA / 16, 256, 0, stream>>>(x, aggB,
        vang + (size_t)l * NB * NA * ND,
        f2oT + (size_t)l * NSQ / 3, f2ob + (size_t)l * ND,
        dwT + (size_t)l * NSQ / 3, dbp + (size_t)l * ND,
        (l < 2) ? (in2fT + (size_t)(l + 1) * NSQ / 3) : nullptr, y);
  }
}